// Round 1
// baseline (276.469 us; speedup 1.0000x reference)
//
#include <hip/hip_runtime.h>

#define BLOCK 256
#define GRID 1024

namespace {
constexpr int C = 21;
constexpr int HW = 512 * 512;          // 262144 = 2^18
constexpr int NPIX = 8 * HW;           // 2097152
constexpr int NGRP = NPIX / 4;         // 524288 float4 groups
constexpr int CH4 = HW / 4;            // channel stride in float4 units
constexpr float EPS = 1e-8f;
constexpr int WS_S = 0;                // [441] S matrix
constexpr int WS_CNT = C * C;          // [21] counts
constexpr int WS_LOGP = C * C + C;     // [1] sum log p[label]
constexpr int WS_FLOATS = C * C + C + 1;
}

__global__ __launch_bounds__(BLOCK) void wce_main(const float* __restrict__ inp,
                                                  const float* __restrict__ tgt,
                                                  float* __restrict__ acc) {
    __shared__ float sS[C * C];
    __shared__ float sCnt[C];
    __shared__ float sRed[BLOCK / 64];

    const int tid = threadIdx.x;
    for (int i = tid; i < C * C; i += BLOCK) sS[i] = 0.f;
    if (tid < C) sCnt[tid] = 0.f;
    __syncthreads();

    float logpy_acc = 0.f;

    for (int g = blockIdx.x * BLOCK + tid; g < NGRP; g += GRID * BLOCK) {
        const int pix0 = g << 2;
        const int n = pix0 >> 18;            // / HW
        const int hw = pix0 & (HW - 1);
        const unsigned base = (unsigned)n * (unsigned)(C * HW) + (unsigned)hw;

        // ---- target argmax over channels ----
        const float4* tp = reinterpret_cast<const float4*>(tgt + base);
        float4 bv = tp[0];
        int bx = 0, by = 0, bz = 0, bw = 0;
#pragma unroll
        for (int c = 1; c < C; ++c) {
            const float4 t = tp[c * CH4];
            if (t.x > bv.x) { bv.x = t.x; bx = c; }
            if (t.y > bv.y) { bv.y = t.y; by = c; }
            if (t.z > bv.z) { bv.z = t.z; bz = c; }
            if (t.w > bv.w) { bv.w = t.w; bw = c; }
        }

        // ---- input load + max + x[label] tracking ----
        const float4* ip = reinterpret_cast<const float4*>(inp + base);
        float4 x[C];
        x[0] = ip[0];
        float4 m = x[0];
        float4 xlab = x[0];
#pragma unroll
        for (int c = 1; c < C; ++c) {
            x[c] = ip[c * CH4];
            m.x = fmaxf(m.x, x[c].x);
            m.y = fmaxf(m.y, x[c].y);
            m.z = fmaxf(m.z, x[c].z);
            m.w = fmaxf(m.w, x[c].w);
            if (bx == c) xlab.x = x[c].x;
            if (by == c) xlab.y = x[c].y;
            if (bz == c) xlab.z = x[c].z;
            if (bw == c) xlab.w = x[c].w;
        }

        // ---- exp + sum (overwrite x with e) ----
        float4 s = make_float4(0.f, 0.f, 0.f, 0.f);
#pragma unroll
        for (int c = 0; c < C; ++c) {
            float4 e;
            e.x = __expf(x[c].x - m.x);
            e.y = __expf(x[c].y - m.y);
            e.z = __expf(x[c].z - m.z);
            e.w = __expf(x[c].w - m.w);
            s.x += e.x; s.y += e.y; s.z += e.z; s.w += e.w;
            x[c] = e;
        }

        // ---- log p[label] ----
        logpy_acc += (xlab.x - m.x - __logf(s.x))
                   + (xlab.y - m.y - __logf(s.y))
                   + (xlab.z - m.z - __logf(s.z))
                   + (xlab.w - m.w - __logf(s.w));

        // ---- scatter p into S columns + counts ----
        const float ix = 1.f / s.x, iy = 1.f / s.y, iz = 1.f / s.z, iw = 1.f / s.w;
#pragma unroll
        for (int c = 0; c < C; ++c) {
            unsafeAtomicAdd(&sS[c * C + bx], x[c].x * ix);
            unsafeAtomicAdd(&sS[c * C + by], x[c].y * iy);
            unsafeAtomicAdd(&sS[c * C + bz], x[c].z * iz);
            unsafeAtomicAdd(&sS[c * C + bw], x[c].w * iw);
        }
        unsafeAtomicAdd(&sCnt[bx], 1.f);
        unsafeAtomicAdd(&sCnt[by], 1.f);
        unsafeAtomicAdd(&sCnt[bz], 1.f);
        unsafeAtomicAdd(&sCnt[bw], 1.f);
    }

    // ---- block reduce logpy ----
#pragma unroll
    for (int off = 32; off > 0; off >>= 1) logpy_acc += __shfl_down(logpy_acc, off);
    if ((tid & 63) == 0) sRed[tid >> 6] = logpy_acc;
    __syncthreads();

    if (tid == 0) {
        float t = 0.f;
        for (int wv = 0; wv < BLOCK / 64; ++wv) t += sRed[wv];
        unsafeAtomicAdd(&acc[WS_LOGP], t);
    }
    for (int i = tid; i < C * C; i += BLOCK) unsafeAtomicAdd(&acc[WS_S + i], sS[i]);
    if (tid < C) unsafeAtomicAdd(&acc[WS_CNT + tid], sCnt[tid]);
}

__global__ void wce_final(const float* __restrict__ acc, float* __restrict__ out) {
    __shared__ float cnts[C];
    __shared__ float red[8];
    const int tid = threadIdx.x;
    if (tid < C) cnts[tid] = acc[WS_CNT + tid];
    __syncthreads();

    float partial = 0.f;
    if (tid < C * C) {
        const int i = tid / C;
        const int j = tid - i * C;
        if (i != j) {
            const float ci = cnts[i], cj = cnts[j];
            if (ci > 0.f && cj > 0.f) {
                const float mcc = acc[WS_S + i * C + i] / ci - acc[WS_S + i * C + j] / cj;
                partial = -0.5f * __logf(0.5f * mcc + 0.5f + EPS);
            }
        }
    }
#pragma unroll
    for (int off = 32; off > 0; off >>= 1) partial += __shfl_down(partial, off);
    if ((tid & 63) == 0) red[tid >> 6] = partial;
    __syncthreads();

    if (tid == 0) {
        float lossd = 0.f;
        for (int wv = 0; wv < 512 / 64; ++wv) lossd += red[wv];
        const float loss = -acc[WS_LOGP] / (float)NPIX;
        out[0] = loss + lossd;
    }
}

extern "C" void kernel_launch(void* const* d_in, const int* in_sizes, int n_in,
                              void* d_out, int out_size, void* d_ws, size_t ws_size,
                              hipStream_t stream) {
    const float* inp = (const float*)d_in[0];
    const float* tgt = (const float*)d_in[1];
    float* acc = (float*)d_ws;
    float* out = (float*)d_out;

    hipMemsetAsync(acc, 0, WS_FLOATS * sizeof(float), stream);
    wce_main<<<GRID, BLOCK, 0, stream>>>(inp, tgt, acc);
    wce_final<<<1, 512, 0, stream>>>(acc, out);
}

// Round 2
// 272.481 us; speedup vs baseline: 1.0146x; 1.0146x over previous
//
#include <hip/hip_runtime.h>

#define BLOCK 512
#define GRID 4096   // GRID*BLOCK == NPIX exactly

namespace {
constexpr int C = 21;
constexpr int HW = 512 * 512;          // 262144 = 2^18
constexpr int NPIX = 8 * HW;           // 2097152
constexpr float EPS = 1e-8f;
constexpr int WS_CNT = C * C;          // counts offset within a copy
constexpr int WS_LOGP = C * C + C;     // logp offset within a copy
constexpr int ACC_USED = C * C + C + 1;   // 463
constexpr int ACC_STRIDE = 464;           // padded copy stride (floats)
constexpr int MAX_COPIES = 64;
}

__global__ __launch_bounds__(BLOCK) void wce_main(const float* __restrict__ inp,
                                                  const float* __restrict__ tgt,
                                                  float* __restrict__ acc,
                                                  int copy_mask) {
    __shared__ float sS[C * C];
    __shared__ float sCnt[C];
    __shared__ float sRed[BLOCK / 64];

    const int tid = threadIdx.x;
    for (int i = tid; i < C * C; i += BLOCK) sS[i] = 0.f;
    if (tid < C) sCnt[tid] = 0.f;
    __syncthreads();

    const int px = blockIdx.x * BLOCK + tid;
    const int n = px >> 18;              // / HW
    const int hw = px & (HW - 1);
    const size_t base = (size_t)n * (size_t)(C * HW) + (size_t)hw;
    const float* __restrict__ tp = tgt + base;
    const float* __restrict__ ip = inp + base;

    // ---- target argmax over channels (21 independent loads in flight) ----
    float bv = tp[0];
    int lab = 0;
#pragma unroll
    for (int c = 1; c < C; ++c) {
        const float v = tp[c * HW];
        if (v > bv) { bv = v; lab = c; }
    }

    // ---- input load (21 independent loads) + max ----
    float x[C];
#pragma unroll
    for (int c = 0; c < C; ++c) x[c] = ip[c * HW];
    float m = x[0];
#pragma unroll
    for (int c = 1; c < C; ++c) m = fmaxf(m, x[c]);

    // x[label] via static-index selects (no dynamic reg indexing -> no scratch)
    float xlab = x[0];
#pragma unroll
    for (int c = 1; c < C; ++c) if (lab == c) xlab = x[c];

    // ---- exp + sum (overwrite x with e) ----
    float s = 0.f;
#pragma unroll
    for (int c = 0; c < C; ++c) { x[c] = __expf(x[c] - m); s += x[c]; }

    const float logpy = xlab - m - __logf(s);

    // ---- scatter p into S column `lab` + count ----
    const float inv = 1.f / s;
#pragma unroll
    for (int c = 0; c < C; ++c) unsafeAtomicAdd(&sS[c * C + lab], x[c] * inv);
    unsafeAtomicAdd(&sCnt[lab], 1.f);

    // ---- block reduce logpy ----
    float lp = logpy;
#pragma unroll
    for (int off = 32; off > 0; off >>= 1) lp += __shfl_down(lp, off);
    if ((tid & 63) == 0) sRed[tid >> 6] = lp;
    __syncthreads();   // covers sRed AND all LDS atomics above

    // ---- flush block partials to one of `copies` global accumulators ----
    float* __restrict__ a = acc + (size_t)(blockIdx.x & copy_mask) * ACC_STRIDE;
    for (int i = tid; i < C * C; i += BLOCK) unsafeAtomicAdd(&a[i], sS[i]);
    if (tid < C) unsafeAtomicAdd(&a[WS_CNT + tid], sCnt[tid]);
    if (tid == 0) {
        float t = 0.f;
#pragma unroll
        for (int wv = 0; wv < BLOCK / 64; ++wv) t += sRed[wv];
        unsafeAtomicAdd(&a[WS_LOGP], t);
    }
}

__global__ void wce_final(const float* __restrict__ acc, float* __restrict__ out,
                          int copies) {
    __shared__ float tot[ACC_USED];
    __shared__ float red[8];
    const int tid = threadIdx.x;

    for (int i = tid; i < ACC_USED; i += 512) {
        float s = 0.f;
        for (int k = 0; k < copies; ++k) s += acc[(size_t)k * ACC_STRIDE + i];
        tot[i] = s;
    }
    __syncthreads();

    float partial = 0.f;
    if (tid < C * C) {
        const int i = tid / C;
        const int j = tid - i * C;
        if (i != j) {
            const float ci = tot[WS_CNT + i], cj = tot[WS_CNT + j];
            if (ci > 0.f && cj > 0.f) {
                const float mcc = tot[i * C + i] / ci - tot[i * C + j] / cj;
                partial = -0.5f * __logf(0.5f * mcc + 0.5f + EPS);
            }
        }
    }
#pragma unroll
    for (int off = 32; off > 0; off >>= 1) partial += __shfl_down(partial, off);
    if ((tid & 63) == 0) red[tid >> 6] = partial;
    __syncthreads();

    if (tid == 0) {
        float lossd = 0.f;
#pragma unroll
        for (int wv = 0; wv < 8; ++wv) lossd += red[wv];
        const float loss = -tot[WS_LOGP] / (float)NPIX;
        out[0] = loss + lossd;
    }
}

extern "C" void kernel_launch(void* const* d_in, const int* in_sizes, int n_in,
                              void* d_out, int out_size, void* d_ws, size_t ws_size,
                              hipStream_t stream) {
    const float* inp = (const float*)d_in[0];
    const float* tgt = (const float*)d_in[1];
    float* acc = (float*)d_ws;
    float* out = (float*)d_out;

    // choose a power-of-two number of accumulator copies that fits d_ws
    int copies = 1;
    const size_t per = (size_t)ACC_STRIDE * sizeof(float);
    while (copies * 2 <= MAX_COPIES && (size_t)(copies * 2) * per <= ws_size) copies *= 2;

    hipMemsetAsync(acc, 0, (size_t)copies * per, stream);
    wce_main<<<GRID, BLOCK, 0, stream>>>(inp, tgt, acc, copies - 1);
    wce_final<<<1, 512, 0, stream>>>(acc, out, copies);
}